// Round 4
// baseline (175.150 us; speedup 1.0000x reference)
//
#include <hip/hip_runtime.h>
#include <hip/hip_bf16.h>
#include <stdint.h>

// out[b,n,o] = sum_t x[b,n,t] * (sum_g y[b,g]*w[g,o,t]*mask[o,t]) + bias[o]
// B=32 N=256 T=1024 O=1024 G=8.  bf16 MFMA path (absmax 0.031 vs thr 0.154).
//
//  K1 prep (R12): latency/occupancy theory.  Three variants (32x8B scatter,
//           16x16B scatter, 32x16B windowed) all ~46-52us with ideal WRITE and
//           VALUBusy 13% -> bound by serial 32-iter loops at 1-2 waves/SIMD.
//           Now: b split across 4 blocks (8 iters/thread), t4 (wv[8][4]=32reg),
//           MIXB 512->4096 short blocks, y via LDS.  w L3-re-read x4 (cheap).
//  K2 gemm (unchanged, [O][B][T] B): mfma_32x32x16, 2x2 waves 64x64, 128x128
//           tile, BK=64, dbuf, xor swizzle, 128B epilogue segments.

#define B_ 32
#define N_ 256
#define T_ 1024
#define O_ 1024
#define G_ 8

#define BM 128
#define BN 128
#define BK 64            // elems; LDS row = 128 B = 8 x 16 B chunks
#define BUFSZ (BM * BK)  // 8192 elems = 16 KiB

#define BROW ((size_t)(B_ * T_))   // [O][B][T]: o-row stride in elems

typedef __attribute__((__ext_vector_type__(8)))  __bf16 bf16x8;
typedef __attribute__((__ext_vector_type__(16))) float  f32x16;

__device__ __forceinline__ unsigned short f2bf(float f) {
    union { float f; uint32_t u; } v; v.f = f;
    uint32_t u = v.u;
    uint32_t r = (u + 0x7fffu + ((u >> 16) & 1u)) >> 16;  // RNE
    return (unsigned short)r;
}

__device__ __forceinline__ uint4 pack8(const float* a) {
    uint4 r;
    r.x = (uint32_t)f2bf(a[0]) | ((uint32_t)f2bf(a[1]) << 16);
    r.y = (uint32_t)f2bf(a[2]) | ((uint32_t)f2bf(a[3]) << 16);
    r.z = (uint32_t)f2bf(a[4]) | ((uint32_t)f2bf(a[5]) << 16);
    r.w = (uint32_t)f2bf(a[6]) | ((uint32_t)f2bf(a[7]) << 16);
    return r;
}

#define MIXB 4096   // 1024 (o,t4)-groups x 4 b-quads
#define CVTB 1024   // 262144 threads, 8 float4 each

// --- K1: fused prologue.
__global__ __launch_bounds__(256) void prep_kernel(
    const float* __restrict__ w,     // [G,O,T]
    const float* __restrict__ mask,  // [O,T]
    const float* __restrict__ y,     // [B,G]
    const float* __restrict__ x,     // [B,N,T]
    unsigned short* __restrict__ Wb, // [O][B][T] bf16
    unsigned short* __restrict__ xb) // [B,N,T] bf16
{
    const int tid = threadIdx.x;
    if (blockIdx.x < MIXB) {
        __shared__ float ys[B_ * G_];          // 1 KiB
        ys[tid] = y[tid];
        __syncthreads();

        // block = (o, b-quad): 256 threads cover t = tid*4, 8 b's each.
        const int bq  = blockIdx.x & 3;
        const int o   = blockIdx.x >> 2;       // 0..1023
        const int t   = tid << 2;

        const float4 m4 = *(const float4*)(mask + (size_t)o * T_ + t);

        float wv[G_][4];
#pragma unroll
        for (int g = 0; g < G_; ++g) {
            const float4 a = *(const float4*)(w + ((size_t)g * O_ + o) * T_ + t);
            wv[g][0] = a.x * m4.x; wv[g][1] = a.y * m4.y;
            wv[g][2] = a.z * m4.z; wv[g][3] = a.w * m4.w;
        }
        unsigned short* dst = Wb + (size_t)o * BROW + t;
        const int bph = (blockIdx.x >> 2) & 7;
#pragma unroll
        for (int bi = 0; bi < 8; ++bi) {
            const int b = bq * 8 + ((bi + bph) & 7);
            const float4 y0 = *(const float4*)(ys + b * G_);      // LDS broadcast
            const float4 y1 = *(const float4*)(ys + b * G_ + 4);
            const float yv[G_] = {y0.x, y0.y, y0.z, y0.w, y1.x, y1.y, y1.z, y1.w};
            float acc[4] = {};
#pragma unroll
            for (int g = 0; g < G_; ++g)
#pragma unroll
                for (int j = 0; j < 4; ++j)
                    acc[j] += yv[g] * wv[g][j];
            ushort4 pk;
            pk.x = f2bf(acc[0]); pk.y = f2bf(acc[1]);
            pk.z = f2bf(acc[2]); pk.w = f2bf(acc[3]);
            *(ushort4*)(dst + (size_t)b * T_) = pk;               // 512B/wave instr
        }
    } else {
        const int i = (blockIdx.x - MIXB) * 256 + tid;
        const float4* x4 = (const float4*)x;
        uint4* o4 = (uint4*)xb;
#pragma unroll
        for (int j = 0; j < 4; ++j) {
            const size_t f4 = (size_t)j * 524288 + (size_t)i * 2;
            const float4 a = x4[f4];
            const float4 b = x4[f4 + 1];
            const float v[8] = {a.x, a.y, a.z, a.w, b.x, b.y, b.z, b.w};
            o4[(size_t)j * 262144 + i] = pack8(v);
        }
    }
}

__device__ __forceinline__ void load16_to_lds(const unsigned short* g, unsigned short* l) {
    __builtin_amdgcn_global_load_lds(
        (const __attribute__((address_space(1))) unsigned char*)g,
        (__attribute__((address_space(3))) unsigned char*)l,
        16, 0, 0);
}

// --- K2: batched GEMM, C = A . B^T, K-major bf16, mfma_32x32x16.
// 256 threads = 4 waves (2m x 2n), wave tile 64x64 = 2x2 of 32x32, acc 2x2xf32x16.
// A-frag: m=lane&31, k=(lane>>5)*8+j; B-frag symmetric.
// C/D: col=lane&31, row=(reg&3)+8*(reg>>2)+4*(lane>>5) [m74/m101].
// LDS chunk c of row r holds global chunk (c ^ (r&7)) -> conflict-free b128.
__global__ __launch_bounds__(256, 2) void gemm_kernel(
    const unsigned short* __restrict__ xb,   // [B][N_][T_] bf16
    const unsigned short* __restrict__ Wb,   // [O][B][T] bf16
    const float* __restrict__ bias,          // [O_]
    float* __restrict__ out)                 // [B][N_][O_] f32
{
    __shared__ __align__(16) unsigned short lA[2 * BUFSZ];  // 32 KiB
    __shared__ __align__(16) unsigned short lB[2 * BUFSZ];  // 32 KiB

    const int tn = blockIdx.x;   // 0..7  (o tiles)
    const int tm = blockIdx.y;   // 0..1  (n tiles)
    const int b  = blockIdx.z;   // 0..31

    const int tid  = threadIdx.x;
    const int lane = tid & 63;
    const int wave = tid >> 6;          // 0..3
    const int wm   = (wave >> 1) * 64;
    const int wn   = (wave & 1) * 64;

    const unsigned short* Ab = xb + (size_t)b * N_ * T_ + (size_t)(tm * BM) * T_;
    const unsigned short* Bb = Wb + (size_t)(tn * BN) * BROW + (size_t)b * T_;

    // staging (256 thr): round i: LDS elem tid*8 + i*2048 -> row tid/8 + i*32
    const int srow   = tid >> 3;                 // 0..31
    const int schunk = (tid & 7) ^ (srow & 7);   // (i*32)&7==0 -> round-invariant
    const unsigned short* ga0 = Ab + (size_t)srow * T_ + schunk * 8;
    const unsigned short* gb0 = Bb + (size_t)srow * BROW + schunk * 8;

#define STAGE(buf, kt)                                                          \
    {                                                                           \
        unsigned short* lad = lA + (buf) * BUFSZ + tid * 8;                     \
        unsigned short* lbd = lB + (buf) * BUFSZ + tid * 8;                     \
        _Pragma("unroll")                                                       \
        for (int i_ = 0; i_ < 4; ++i_) {                                        \
            load16_to_lds(ga0 + (kt) + (size_t)(i_ * 32) * T_, lad + i_ * 2048);\
            load16_to_lds(gb0 + (kt) + (size_t)(i_ * 32) * BROW, lbd + i_ * 2048);\
        }                                                                       \
    }

    f32x16 acc[2][2] = {};

    const int fr   = lane & 31;      // fragment row within 32
    const int half = lane >> 5;      // k-half 0/1 (8 elems each)
    const int sw   = fr & 7;         // swizzle term (wm, mi*32 are multiples of 8)

#define COMPUTE(buf)                                                            \
    {                                                                           \
        const unsigned short* la = lA + (buf) * BUFSZ;                          \
        const unsigned short* lb = lB + (buf) * BUFSZ;                          \
        _Pragma("unroll")                                                       \
        for (int ks = 0; ks < 4; ++ks) {                                        \
            const int cp = (((ks * 2 + half)) ^ sw) * 8;                        \
            bf16x8 afr[2], bfr[2];                                              \
            _Pragma("unroll")                                                   \
            for (int i_ = 0; i_ < 2; ++i_)                                      \
                afr[i_] = *(const bf16x8*)(la + (wm + i_ * 32 + fr) * BK + cp); \
            _Pragma("unroll")                                                   \
            for (int i_ = 0; i_ < 2; ++i_)                                      \
                bfr[i_] = *(const bf16x8*)(lb + (wn + i_ * 32 + fr) * BK + cp); \
            _Pragma("unroll")                                                   \
            for (int mi = 0; mi < 2; ++mi)                                      \
                _Pragma("unroll")                                               \
                for (int ni = 0; ni < 2; ++ni)                                  \
                    acc[mi][ni] = __builtin_amdgcn_mfma_f32_32x32x16_bf16(      \
                        afr[mi], bfr[ni], acc[mi][ni], 0, 0, 0);                \
        }                                                                       \
    }

    STAGE(0, 0)
    for (int kt = 0; kt < T_; kt += 2 * BK) {
        __syncthreads();                       // buf0(kt) staged
        STAGE(1, kt + BK)                      // prefetch buf1
        COMPUTE(0)
        __syncthreads();                       // buf1 staged; buf0 reads done
        if (kt + 2 * BK < T_) STAGE(0, kt + 2 * BK)
        COMPUTE(1)
    }

    // Epilogue: D col=lane&31, row=(reg&3)+8*(reg>>2)+4*(lane>>5)  + bias.
    float* outb = out + (size_t)b * N_ * O_ + (size_t)(tm * BM) * O_ + (tn * BN);
    const int cn = lane & 31;
    const int rb = (lane >> 5) * 4;
#pragma unroll
    for (int ni = 0; ni < 2; ++ni) {
        const int col = wn + ni * 32 + cn;
        const float bv = bias[tn * BN + col];
#pragma unroll
        for (int mi = 0; mi < 2; ++mi) {
#pragma unroll
            for (int r = 0; r < 16; ++r) {
                const int row = wm + mi * 32 + rb + (r & 3) + 8 * (r >> 2);
                outb[(size_t)row * O_ + col] = acc[mi][ni][r] + bv;
            }
        }
    }
}

// --- Fallback (ws too small): correct fp32 path.
__global__ __launch_bounds__(256) void naive_kernel(
    const float* __restrict__ x, const float* __restrict__ y,
    const float* __restrict__ w, const float* __restrict__ mask,
    const float* __restrict__ bias, float* __restrict__ out)
{
    const int oc = blockIdx.x & 3;
    const int n  = (blockIdx.x >> 2) & (N_ - 1);
    const int b  = blockIdx.x >> 10;

    __shared__ float xs[T_];
    __shared__ float ys[G_];
    const float* xrow = x + ((size_t)b * N_ + n) * T_;
    for (int i = threadIdx.x; i < T_ / 4; i += 256)
        ((float4*)xs)[i] = ((const float4*)xrow)[i];
    if (threadIdx.x < G_) ys[threadIdx.x] = y[b * G_ + threadIdx.x];
    __syncthreads();

    const int o = oc * 256 + threadIdx.x;
    float acc = 0.f;
    for (int t = 0; t < T_; t += 4) {
        const float4 m4 = *(const float4*)(mask + (size_t)o * T_ + t);
        float4 s = {0.f, 0.f, 0.f, 0.f};
#pragma unroll
        for (int g = 0; g < G_; ++g) {
            const float4 w4 = *(const float4*)(w + ((size_t)g * O_ + o) * T_ + t);
            const float yv = ys[g];
            s.x += yv * w4.x; s.y += yv * w4.y; s.z += yv * w4.z; s.w += yv * w4.w;
        }
        acc += xs[t] * m4.x * s.x + xs[t + 1] * m4.y * s.y
             + xs[t + 2] * m4.z * s.z + xs[t + 3] * m4.w * s.w;
    }
    out[((size_t)b * N_ + n) * O_ + o] = acc + bias[o];
}

extern "C" void kernel_launch(void* const* d_in, const int* in_sizes, int n_in,
                              void* d_out, int out_size, void* d_ws, size_t ws_size,
                              hipStream_t stream) {
    const float* x    = (const float*)d_in[0];
    const float* y    = (const float*)d_in[1];
    const float* w    = (const float*)d_in[2];
    const float* mask = (const float*)d_in[3];
    const float* bias = (const float*)d_in[4];
    float* out = (float*)d_out;

    const size_t wb_bytes = (size_t)O_ * B_ * T_ * sizeof(unsigned short); // 64 MiB
    const size_t xb_bytes = (size_t)B_ * N_ * T_ * sizeof(unsigned short); // 16 MiB

    if (ws_size >= wb_bytes + xb_bytes) {
        unsigned short* Wb = (unsigned short*)d_ws;
        unsigned short* xb = (unsigned short*)((char*)d_ws + wb_bytes);
        prep_kernel<<<MIXB + CVTB, 256, 0, stream>>>(w, mask, y, x, Wb, xb);
        dim3 grid(O_ / BN, N_ / BM, B_);
        gemm_kernel<<<grid, 256, 0, stream>>>(xb, Wb, bias, out);
    } else {
        naive_kernel<<<B_ * N_ * (O_ / 256), 256, 0, stream>>>(x, y, w, mask, bias, out);
    }
}

// Round 5
// 150.604 us; speedup vs baseline: 1.1630x; 1.1630x over previous
//
#include <hip/hip_runtime.h>
#include <hip/hip_bf16.h>
#include <stdint.h>

// out[b,n,o] = sum_t x[b,n,t] * (sum_g y[b,g]*w[g,o,t]*mask[o,t]) + bias[o]
// B=32 N=256 T=1024 O=1024 G=8.  bf16 MFMA path (absmax 0.031 vs thr 0.154).
//
//  K1 prep (R13): R1-best structure (45.5us, [B][O][T], 32b x 4t, FETCH 35MB)
//           + y via LDS broadcast (-64 VMEM/thread).  Four mix variants showed
//           duration == fabric_traffic / ~3 TB/s regardless of store pattern or
//           occupancy -> minimize traffic, keep R1 shape.
//  K2 gemm (R13): grid reordered to (b, tm, tn) so XCD = b%8: all 16 blocks
//           sharing b land on one XCD -> A-tile (x8 reuse) and B-tile (x2)
//           served from L2, fabric 384->~208 MB.  Kernel body unchanged:
//           mfma_32x32x16, 2x2 waves 64x64, 128x128 tile, BK=64, dbuf, swizzle.

#define B_ 32
#define N_ 256
#define T_ 1024
#define O_ 1024
#define G_ 8

#define WSTRIDE ((size_t)(O_ * T_ + 2048))   // padded b-slice stride, elems

#define BM 128
#define BN 128
#define BK 64            // elems; LDS row = 128 B = 8 x 16 B chunks
#define BUFSZ (BM * BK)  // 8192 elems = 16 KiB

typedef __attribute__((__ext_vector_type__(8)))  __bf16 bf16x8;
typedef __attribute__((__ext_vector_type__(16))) float  f32x16;

__device__ __forceinline__ unsigned short f2bf(float f) {
    union { float f; uint32_t u; } v; v.f = f;
    uint32_t u = v.u;
    uint32_t r = (u + 0x7fffu + ((u >> 16) & 1u)) >> 16;  // RNE
    return (unsigned short)r;
}

__device__ __forceinline__ uint4 pack8(const float* a) {
    uint4 r;
    r.x = (uint32_t)f2bf(a[0]) | ((uint32_t)f2bf(a[1]) << 16);
    r.y = (uint32_t)f2bf(a[2]) | ((uint32_t)f2bf(a[3]) << 16);
    r.z = (uint32_t)f2bf(a[4]) | ((uint32_t)f2bf(a[5]) << 16);
    r.w = (uint32_t)f2bf(a[6]) | ((uint32_t)f2bf(a[7]) << 16);
    return r;
}

#define MIXB 1024   // O*T/4 threads / 256
#define CVTB 1024   // 262144 threads, 8 float4 each

// --- K1: fused prologue (R1 structure + y-LDS).
__global__ __launch_bounds__(256) void prep_kernel(
    const float* __restrict__ w,     // [G,O,T]
    const float* __restrict__ mask,  // [O,T]
    const float* __restrict__ y,     // [B,G]
    const float* __restrict__ x,     // [B,N,T]
    unsigned short* __restrict__ Wb, // [B][WSTRIDE] bf16 (padded)
    unsigned short* __restrict__ xb) // [B,N,T] bf16
{
    const int tid = threadIdx.x;
    if (blockIdx.x < MIXB) {
        __shared__ float ys[B_ * G_];          // 1 KiB
        ys[tid] = y[tid];
        __syncthreads();

        const int idx = blockIdx.x * 256 + tid;   // over O*T/4
        const int o   = idx >> 8;
        const int t   = (idx & 255) << 2;

        const float4 m4 = *(const float4*)(mask + (size_t)o * T_ + t);

        float wv[G_][4];
#pragma unroll
        for (int g = 0; g < G_; ++g) {
            const float4 a = *(const float4*)(w + ((size_t)g * O_ + o) * T_ + t);
            wv[g][0] = a.x * m4.x; wv[g][1] = a.y * m4.y;
            wv[g][2] = a.z * m4.z; wv[g][3] = a.w * m4.w;
        }
        unsigned short* dst = Wb + (size_t)o * T_ + t;
        const int bph = blockIdx.x & (B_ - 1);
#pragma unroll 4
        for (int bi = 0; bi < B_; ++bi) {
            const int b = (bi + bph) & (B_ - 1);
            const float4 y0 = *(const float4*)(ys + b * G_);      // LDS broadcast
            const float4 y1 = *(const float4*)(ys + b * G_ + 4);
            const float yv[G_] = {y0.x, y0.y, y0.z, y0.w, y1.x, y1.y, y1.z, y1.w};
            float acc[4] = {};
#pragma unroll
            for (int g = 0; g < G_; ++g)
#pragma unroll
                for (int j = 0; j < 4; ++j)
                    acc[j] += yv[g] * wv[g][j];
            ushort4 pk;
            pk.x = f2bf(acc[0]); pk.y = f2bf(acc[1]);
            pk.z = f2bf(acc[2]); pk.w = f2bf(acc[3]);
            *(ushort4*)(dst + (size_t)b * WSTRIDE) = pk;
        }
    } else {
        const int i = (blockIdx.x - MIXB) * 256 + tid;
        const float4* x4 = (const float4*)x;
        uint4* o4 = (uint4*)xb;
#pragma unroll
        for (int j = 0; j < 4; ++j) {
            const size_t f4 = (size_t)j * 524288 + (size_t)i * 2;
            const float4 a = x4[f4];
            const float4 b = x4[f4 + 1];
            const float v[8] = {a.x, a.y, a.z, a.w, b.x, b.y, b.z, b.w};
            o4[(size_t)j * 262144 + i] = pack8(v);
        }
    }
}

__device__ __forceinline__ void load16_to_lds(const unsigned short* g, unsigned short* l) {
    __builtin_amdgcn_global_load_lds(
        (const __attribute__((address_space(1))) unsigned char*)g,
        (__attribute__((address_space(3))) unsigned char*)l,
        16, 0, 0);
}

// --- K2: batched GEMM, C = A . B^T, K-major bf16, mfma_32x32x16.
// 256 threads = 4 waves (2m x 2n), wave tile 64x64 = 2x2 of 32x32, acc 2x2xf32x16.
// A-frag: m=lane&31, k=(lane>>5)*8+j; B-frag symmetric.
// C/D: col=lane&31, row=(reg&3)+8*(reg>>2)+4*(lane>>5) [m74/m101].
// LDS chunk c of row r holds global chunk (c ^ (r&7)) -> conflict-free b128.
// Grid = (b, tm, tn): XCD = linear%8 = b%8 -> same-b blocks colocate on an XCD.
__global__ __launch_bounds__(256, 2) void gemm_kernel(
    const unsigned short* __restrict__ xb,   // [B][N_][T_] bf16
    const unsigned short* __restrict__ Wb,   // [B][WSTRIDE] bf16 (padded)
    const float* __restrict__ bias,          // [O_]
    float* __restrict__ out)                 // [B][N_][O_] f32
{
    __shared__ __align__(16) unsigned short lA[2 * BUFSZ];  // 32 KiB
    __shared__ __align__(16) unsigned short lB[2 * BUFSZ];  // 32 KiB

    const int b  = blockIdx.x;   // 0..31  (XCD = b%8)
    const int tm = blockIdx.y;   // 0..1   (n tiles)
    const int tn = blockIdx.z;   // 0..7   (o tiles)

    const int tid  = threadIdx.x;
    const int lane = tid & 63;
    const int wave = tid >> 6;          // 0..3
    const int wm   = (wave >> 1) * 64;
    const int wn   = (wave & 1) * 64;

    const unsigned short* Ab = xb + (size_t)b * N_ * T_ + (size_t)(tm * BM) * T_;
    const unsigned short* Bb = Wb + (size_t)b * WSTRIDE + (size_t)(tn * BN) * T_;

    // staging (256 thr): round i: LDS elem tid*8 + i*2048 -> row tid/8 + i*32
    const int srow   = tid >> 3;                 // 0..31
    const int schunk = (tid & 7) ^ (srow & 7);   // (i*32)&7==0 -> round-invariant
    const unsigned short* ga0 = Ab + (size_t)srow * T_ + schunk * 8;
    const unsigned short* gb0 = Bb + (size_t)srow * T_ + schunk * 8;

#define STAGE(buf, kt)                                                          \
    {                                                                           \
        unsigned short* lad = lA + (buf) * BUFSZ + tid * 8;                     \
        unsigned short* lbd = lB + (buf) * BUFSZ + tid * 8;                     \
        _Pragma("unroll")                                                       \
        for (int i_ = 0; i_ < 4; ++i_) {                                        \
            load16_to_lds(ga0 + (kt) + (size_t)(i_ * 32) * T_, lad + i_ * 2048);\
            load16_to_lds(gb0 + (kt) + (size_t)(i_ * 32) * T_, lbd + i_ * 2048);\
        }                                                                       \
    }

    f32x16 acc[2][2] = {};

    const int fr   = lane & 31;      // fragment row within 32
    const int half = lane >> 5;      // k-half 0/1 (8 elems each)
    const int sw   = fr & 7;         // swizzle term (wm, mi*32 are multiples of 8)

#define COMPUTE(buf)                                                            \
    {                                                                           \
        const unsigned short* la = lA + (buf) * BUFSZ;                          \
        const unsigned short* lb = lB + (buf) * BUFSZ;                          \
        _Pragma("unroll")                                                       \
        for (int ks = 0; ks < 4; ++ks) {                                        \
            const int cp = (((ks * 2 + half)) ^ sw) * 8;                        \
            bf16x8 afr[2], bfr[2];                                              \
            _Pragma("unroll")                                                   \
            for (int i_ = 0; i_ < 2; ++i_)                                      \
                afr[i_] = *(const bf16x8*)(la + (wm + i_ * 32 + fr) * BK + cp); \
            _Pragma("unroll")                                                   \
            for (int i_ = 0; i_ < 2; ++i_)                                      \
                bfr[i_] = *(const bf16x8*)(lb + (wn + i_ * 32 + fr) * BK + cp); \
            _Pragma("unroll")                                                   \
            for (int mi = 0; mi < 2; ++mi)                                      \
                _Pragma("unroll")                                               \
                for (int ni = 0; ni < 2; ++ni)                                  \
                    acc[mi][ni] = __builtin_amdgcn_mfma_f32_32x32x16_bf16(      \
                        afr[mi], bfr[ni], acc[mi][ni], 0, 0, 0);                \
        }                                                                       \
    }

    STAGE(0, 0)
    for (int kt = 0; kt < T_; kt += 2 * BK) {
        __syncthreads();                       // buf0(kt) staged
        STAGE(1, kt + BK)                      // prefetch buf1
        COMPUTE(0)
        __syncthreads();                       // buf1 staged; buf0 reads done
        if (kt + 2 * BK < T_) STAGE(0, kt + 2 * BK)
        COMPUTE(1)
    }

    // Epilogue: D col=lane&31, row=(reg&3)+8*(reg>>2)+4*(lane>>5)  + bias.
    float* outb = out + (size_t)b * N_ * O_ + (size_t)(tm * BM) * O_ + (tn * BN);
    const int cn = lane & 31;
    const int rb = (lane >> 5) * 4;
#pragma unroll
    for (int ni = 0; ni < 2; ++ni) {
        const int col = wn + ni * 32 + cn;
        const float bv = bias[tn * BN + col];
#pragma unroll
        for (int mi = 0; mi < 2; ++mi) {
#pragma unroll
            for (int r = 0; r < 16; ++r) {
                const int row = wm + mi * 32 + rb + (r & 3) + 8 * (r >> 2);
                outb[(size_t)row * O_ + col] = acc[mi][ni][r] + bv;
            }
        }
    }
}

// --- Fallback (ws too small): correct fp32 path.
__global__ __launch_bounds__(256) void naive_kernel(
    const float* __restrict__ x, const float* __restrict__ y,
    const float* __restrict__ w, const float* __restrict__ mask,
    const float* __restrict__ bias, float* __restrict__ out)
{
    const int oc = blockIdx.x & 3;
    const int n  = (blockIdx.x >> 2) & (N_ - 1);
    const int b  = blockIdx.x >> 10;

    __shared__ float xs[T_];
    __shared__ float ys[G_];
    const float* xrow = x + ((size_t)b * N_ + n) * T_;
    for (int i = threadIdx.x; i < T_ / 4; i += 256)
        ((float4*)xs)[i] = ((const float4*)xrow)[i];
    if (threadIdx.x < G_) ys[threadIdx.x] = y[b * G_ + threadIdx.x];
    __syncthreads();

    const int o = oc * 256 + threadIdx.x;
    float acc = 0.f;
    for (int t = 0; t < T_; t += 4) {
        const float4 m4 = *(const float4*)(mask + (size_t)o * T_ + t);
        float4 s = {0.f, 0.f, 0.f, 0.f};
#pragma unroll
        for (int g = 0; g < G_; ++g) {
            const float4 w4 = *(const float4*)(w + ((size_t)g * O_ + o) * T_ + t);
            const float yv = ys[g];
            s.x += yv * w4.x; s.y += yv * w4.y; s.z += yv * w4.z; s.w += yv * w4.w;
        }
        acc += xs[t] * m4.x * s.x + xs[t + 1] * m4.y * s.y
             + xs[t + 2] * m4.z * s.z + xs[t + 3] * m4.w * s.w;
    }
    out[((size_t)b * N_ + n) * O_ + o] = acc + bias[o];
}

extern "C" void kernel_launch(void* const* d_in, const int* in_sizes, int n_in,
                              void* d_out, int out_size, void* d_ws, size_t ws_size,
                              hipStream_t stream) {
    const float* x    = (const float*)d_in[0];
    const float* y    = (const float*)d_in[1];
    const float* w    = (const float*)d_in[2];
    const float* mask = (const float*)d_in[3];
    const float* bias = (const float*)d_in[4];
    float* out = (float*)d_out;

    const size_t wb_bytes = (size_t)B_ * WSTRIDE * sizeof(unsigned short); // 64 MiB + 128 KB
    const size_t xb_bytes = (size_t)B_ * N_ * T_ * sizeof(unsigned short); // 16 MiB

    if (ws_size >= wb_bytes + xb_bytes) {
        unsigned short* Wb = (unsigned short*)d_ws;
        unsigned short* xb = (unsigned short*)((char*)d_ws + wb_bytes);
        prep_kernel<<<MIXB + CVTB, 256, 0, stream>>>(w, mask, y, x, Wb, xb);
        dim3 grid(B_, N_ / BM, O_ / BN);   // x=b -> XCD=b%8: A,B L2-resident
        gemm_kernel<<<grid, 256, 0, stream>>>(xb, Wb, bias, out);
    } else {
        naive_kernel<<<B_ * N_ * (O_ / 256), 256, 0, stream>>>(x, y, w, mask, bias, out);
    }
}